// Round 5
// baseline (218.822 us; speedup 1.0000x reference)
//
#include <hip/hip_runtime.h>

#define N_NODES 50000
#define N_EDGES 800000
#define D 128

#define NSLICE 8
#define SLICE_STRIDE (N_NODES * 8)   // uints per slice plane (1.6 MB)

// ---------------------------------------------------------------------------
// Workspace layout (bytes, 16B-aligned):
//   H16s     : N_NODES*D bf16 (slice-major) = 12,800,000
//   counts   : N_NODES ints        =    200,000
//   offsets  : (N_NODES+1) ints    =    200,016 (padded)
//   rank     : N_EDGES ints        =  3,200,000
//   spair    : N_EDGES int2        =  6,400,000
//   partials : 256 ints            =      1,024
//   blockoffs: 256 ints            =      1,024
// ---------------------------------------------------------------------------
#define WS_H_OFF       0
#define WS_COUNTS_OFF  (12800000)
#define WS_OFFSETS_OFF (WS_COUNTS_OFF + 200000)
#define WS_RANK_OFF    (WS_OFFSETS_OFF + 200016)
#define WS_SPAIR_OFF   (WS_RANK_OFF + 3200000)
#define WS_PART_OFF    (WS_SPAIR_OFF + 6400000)
#define WS_BOFF_OFF    (WS_PART_OFF + 1024)

#define SCAN_BLOCKS 196   // ceil(50000/256)

// f32 -> bf16 round-to-nearest-even
__device__ __forceinline__ unsigned int f2bf(float f) {
    unsigned int u = __float_as_uint(f);
    unsigned int r = u + 0x7FFFu + ((u >> 16) & 1u);
    return r >> 16;
}
__device__ __forceinline__ float bf_lo(unsigned int u) {
    return __uint_as_float(u << 16);
}
__device__ __forceinline__ float bf_hi(unsigned int u) {
    return __uint_as_float(u & 0xFFFF0000u);
}

// ---------------------------------------------------------------------------
__global__ void zero_counts_kernel(int* __restrict__ counts, int n) {
    int i = blockIdx.x * blockDim.x + threadIdx.x;
    if (i < n) counts[i] = 0;
}

// ---------------------------------------------------------------------------
// Histogram + per-edge rank; 4 edges/thread for atomic latency hiding.
// ---------------------------------------------------------------------------
__global__ void hist_rank_kernel(const int* __restrict__ row,
                                 int* __restrict__ counts,
                                 int* __restrict__ rank) {
    int i = blockIdx.x * blockDim.x + threadIdx.x;
    int e = i * 4;
    if (e >= N_EDGES) return;
    int4 rr = *reinterpret_cast<const int4*>(row + e);
    int k0 = atomicAdd(&counts[rr.x], 1);
    int k1 = atomicAdd(&counts[rr.y], 1);
    int k2 = atomicAdd(&counts[rr.z], 1);
    int k3 = atomicAdd(&counts[rr.w], 1);
    *reinterpret_cast<int4*>(rank + e) = make_int4(k0, k1, k2, k3);
}

// ---------------------------------------------------------------------------
// Scan stage 1: per-block (256-elem) sums -> partials[block]
// ---------------------------------------------------------------------------
__global__ __launch_bounds__(256) void scan_partials_kernel(const int* __restrict__ counts,
                                                            int* __restrict__ partials) {
    __shared__ int red[4];
    int t = threadIdx.x;
    int i = blockIdx.x * 256 + t;
    int v = (i < N_NODES) ? counts[i] : 0;
    #pragma unroll
    for (int off = 32; off > 0; off >>= 1) v += __shfl_down(v, off, 64);
    if ((t & 63) == 0) red[t >> 6] = v;
    __syncthreads();
    if (t == 0) partials[blockIdx.x] = red[0] + red[1] + red[2] + red[3];
}

// ---------------------------------------------------------------------------
// Scan stage 2: single block scans SCAN_BLOCKS partials -> blockoffs (excl).
// ---------------------------------------------------------------------------
__global__ __launch_bounds__(256) void scan_block_kernel(const int* __restrict__ partials,
                                                         int* __restrict__ blockoffs,
                                                         int* __restrict__ offsets) {
    __shared__ int sh[256];
    int t = threadIdx.x;
    int v = (t < SCAN_BLOCKS) ? partials[t] : 0;
    sh[t] = v;
    __syncthreads();
    #pragma unroll
    for (int off = 1; off < 256; off <<= 1) {
        int x = sh[t];
        int a = (t >= off) ? sh[t - off] : 0;
        __syncthreads();
        sh[t] = x + a;
        __syncthreads();
    }
    blockoffs[t] = (t == 0) ? 0 : sh[t - 1];
    if (t == 255) offsets[N_NODES] = sh[255];
}

// ---------------------------------------------------------------------------
// Scan stage 3: per-block local exclusive scan + blockoff -> offsets
// ---------------------------------------------------------------------------
__global__ __launch_bounds__(256) void scan_final_kernel(const int* __restrict__ counts,
                                                         const int* __restrict__ blockoffs,
                                                         int* __restrict__ offsets) {
    __shared__ int sh[256];
    int t = threadIdx.x;
    int i = blockIdx.x * 256 + t;
    int v = (i < N_NODES) ? counts[i] : 0;
    sh[t] = v;
    __syncthreads();
    #pragma unroll
    for (int off = 1; off < 256; off <<= 1) {
        int x = sh[t];
        int a = (t >= off) ? sh[t - off] : 0;
        __syncthreads();
        sh[t] = x + a;
        __syncthreads();
    }
    if (i < N_NODES)
        offsets[i] = blockoffs[blockIdx.x] + ((t == 0) ? 0 : sh[t - 1]);
}

// ---------------------------------------------------------------------------
// Bucket (atomic-free): spair[offsets[row[e]] + rank[e]] = (col[e], vals[e])
// ---------------------------------------------------------------------------
__global__ void bucket_kernel(const int* __restrict__ row, const int* __restrict__ col,
                              const float* __restrict__ vals,
                              const int* __restrict__ offsets,
                              const int* __restrict__ rank,
                              int2* __restrict__ spair) {
    int e = blockIdx.x * blockDim.x + threadIdx.x;
    if (e >= N_EDGES) return;
    int r = row[e];
    int pos = offsets[r] + rank[e];
    spair[pos] = make_int2(col[e], __float_as_int(vals[e]));
}

// ---------------------------------------------------------------------------
// GEMM: H16s = bf16(X @ W^T), written slice-major:
//   H16s[s*SLICE_STRIDE + row*8 + cu] holds cols (16s+2cu, 16s+2cu+1)
// ---------------------------------------------------------------------------
__global__ __launch_bounds__(256) void gemm_xwT_kernel(const float* __restrict__ X,
                                                       const float* __restrict__ W,
                                                       unsigned int* __restrict__ H16) {
    __shared__ float Wt[D * D];    // 64 KiB
    __shared__ float xs[32 * D];   // 16 KiB
    const int t = threadIdx.x;
    const int base = blockIdx.x * 32;

    #pragma unroll
    for (int i = 0; i < 16; ++i) {
        int idx4 = t + i * 256;
        float4 w4 = reinterpret_cast<const float4*>(W)[idx4];
        int o  = idx4 >> 5;
        int d0 = (idx4 & 31) << 2;
        int oc = (o + d0) & 127;
        Wt[(d0 + 0) * D + oc] = w4.x;
        Wt[(d0 + 1) * D + oc] = w4.y;
        Wt[(d0 + 2) * D + oc] = w4.z;
        Wt[(d0 + 3) * D + oc] = w4.w;
    }

    #pragma unroll
    for (int i = 0; i < 4; ++i) {
        int idx4 = t + i * 256;
        int r  = idx4 >> 5;
        int d4 = idx4 & 31;
        int row = base + r;
        float4 x4 = {0.f, 0.f, 0.f, 0.f};
        if (row < N_NODES)
            x4 = reinterpret_cast<const float4*>(X + (size_t)row * D)[d4];
        reinterpret_cast<float4*>(xs)[idx4] = x4;
    }
    __syncthreads();

    const int rg = t >> 5;   // 0..7
    const int cg = t & 31;   // 0..31

    float acc[4][4];
    #pragma unroll
    for (int rr = 0; rr < 4; ++rr)
        #pragma unroll
        for (int cc = 0; cc < 4; ++cc) acc[rr][cc] = 0.f;

    #pragma unroll 4
    for (int d0 = 0; d0 < D; d0 += 4) {
        int jb = (cg * 4 + d0) & 127;
        float4 wc[4];
        #pragma unroll
        for (int k = 0; k < 4; ++k)
            wc[k] = *reinterpret_cast<const float4*>(&Wt[(d0 + k) * D + jb]);
        float4 xr[4];
        #pragma unroll
        for (int rr = 0; rr < 4; ++rr)
            xr[rr] = *reinterpret_cast<const float4*>(&xs[(rg * 4 + rr) * D + d0]);

        #pragma unroll
        for (int rr = 0; rr < 4; ++rr) {
            const float xv[4] = {xr[rr].x, xr[rr].y, xr[rr].z, xr[rr].w};
            #pragma unroll
            for (int k = 0; k < 4; ++k) {
                acc[rr][0] += xv[k] * wc[k].x;
                acc[rr][1] += xv[k] * wc[k].y;
                acc[rr][2] += xv[k] * wc[k].z;
                acc[rr][3] += xv[k] * wc[k].w;
            }
        }
    }

    const int s  = cg >> 2;          // slice
    const int cu = (cg & 3) << 1;    // uint index within slice (0,2,4,6)
    #pragma unroll
    for (int rr = 0; rr < 4; ++rr) {
        int row = base + rg * 4 + rr;
        if (row < N_NODES) {
            uint2 packed;
            packed.x = f2bf(acc[rr][0]) | (f2bf(acc[rr][1]) << 16);
            packed.y = f2bf(acc[rr][2]) | (f2bf(acc[rr][3]) << 16);
            *reinterpret_cast<uint2*>(H16 + (size_t)s * SLICE_STRIDE + row * 8 + cu) = packed;
        }
    }
}

// ---------------------------------------------------------------------------
// Sliced aggregate: block bid -> slice s = bid&7 (pins slice to XCD via the
// default round-robin block->XCD mapping; each XCD's 1.6MB slice plane is
// L2-resident). 4 waves/block = 4 rows. Wave: 8 edge-groups x 8 lanes;
// lane (eg,c) accumulates cols (16s+2c, 16s+2c+1) over edges beg+eg, +8, ...
// then shfl_xor-reduce across eg and lanes eg==0 write out + bias.
// ---------------------------------------------------------------------------
__global__ __launch_bounds__(256) void aggregate_sliced_kernel(
        const int* __restrict__ offsets, const int2* __restrict__ spair,
        const unsigned int* __restrict__ H16s,
        const float* __restrict__ b, float* __restrict__ out) {
    const int bid = blockIdx.x;
    const int s   = bid & 7;
    const int rg  = bid >> 3;
    const int row = rg * 4 + (threadIdx.x >> 6);
    const int lane = threadIdx.x & 63;
    const int eg = lane >> 3;   // 0..7
    const int c  = lane & 7;    // 0..7

    const unsigned int* plane = H16s + (size_t)s * SLICE_STRIDE;
    const int beg = offsets[row];
    const int end = offsets[row + 1];

    float ax = 0.f, ay = 0.f;
    for (int i = beg + eg; i < end; i += 8) {
        int2 sv = spair[i];
        float v = __int_as_float(sv.y);
        unsigned int h = plane[(size_t)sv.x * 8 + c];
        ax += v * bf_lo(h);
        ay += v * bf_hi(h);
    }
    #pragma unroll
    for (int off = 8; off < 64; off <<= 1) {
        ax += __shfl_xor(ax, off, 64);
        ay += __shfl_xor(ay, off, 64);
    }
    if (eg == 0) {
        float2 bb = reinterpret_cast<const float2*>(b)[s * 8 + c];
        float2 res = {ax + bb.x, ay + bb.y};
        reinterpret_cast<float2*>(out + (size_t)row * D)[s * 8 + c] = res;
    }
}

// ---------------------------------------------------------------------------
extern "C" void kernel_launch(void* const* d_in, const int* in_sizes, int n_in,
                              void* d_out, int out_size, void* d_ws, size_t ws_size,
                              hipStream_t stream) {
    const int*   adj_row  = (const int*)d_in[0];
    const int*   adj_col  = (const int*)d_in[1];
    const float* adj_vals = (const float*)d_in[2];
    const float* features = (const float*)d_in[3];
    const float* W        = (const float*)d_in[4];
    const float* b        = (const float*)d_in[5];
    float*       out      = (float*)d_out;

    char* ws = (char*)d_ws;
    unsigned int* H16s      = (unsigned int*)(ws + WS_H_OFF);
    int*          counts    = (int*)  (ws + WS_COUNTS_OFF);
    int*          offsets   = (int*)  (ws + WS_OFFSETS_OFF);
    int*          rank      = (int*)  (ws + WS_RANK_OFF);
    int2*         spair     = (int2*) (ws + WS_SPAIR_OFF);
    int*          partials  = (int*)  (ws + WS_PART_OFF);
    int*          blockoffs = (int*)  (ws + WS_BOFF_OFF);

    // 1. zero counts
    zero_counts_kernel<<<(N_NODES + 255) / 256, 256, 0, stream>>>(counts, N_NODES);
    // 2. histogram + per-edge rank (the only atomic pass)
    {
        int threads = N_EDGES / 4;
        hist_rank_kernel<<<(threads + 255) / 256, 256, 0, stream>>>(adj_row, counts, rank);
    }
    // 3. hierarchical scan -> offsets
    scan_partials_kernel<<<SCAN_BLOCKS, 256, 0, stream>>>(counts, partials);
    scan_block_kernel<<<1, 256, 0, stream>>>(partials, blockoffs, offsets);
    scan_final_kernel<<<SCAN_BLOCKS, 256, 0, stream>>>(counts, blockoffs, offsets);
    // 4. bucket (col,val) by row — atomic-free
    bucket_kernel<<<N_EDGES / 256, 256, 0, stream>>>(adj_row, adj_col, adj_vals,
                                                     offsets, rank, spair);
    // 5. H16s = bf16(X @ W^T), slice-major
    gemm_xwT_kernel<<<(N_NODES + 31) / 32, 256, 0, stream>>>(features, W, H16s);
    // 6. sliced aggregate: out = b + segment_sum(val * H[col]), slice per XCD
    {
        int blocks = (N_NODES / 4) * NSLICE;   // 12500 * 8 = 100000
        aggregate_sliced_kernel<<<blocks, 256, 0, stream>>>(offsets, spair, H16s, b, out);
    }
}

// Round 6
// 132.162 us; speedup vs baseline: 1.6557x; 1.6557x over previous
//
#include <hip/hip_runtime.h>
#include <hip/hip_fp16.h>

#define N_NODES 50000
#define N_EDGES 800000
#define D 128
#define PAD 56   // padded-CSR slots per row; P(Poisson(16) > 56) ~ 1e-14/node

// ---------------------------------------------------------------------------
// Workspace layout (bytes, 16B-aligned):
//   H16    : N_NODES*64 uints (bf16x2 packed) = 12,800,000
//   ecsr   : N_NODES*PAD uints (col u16 | f16 val << 16) = 11,200,000
//   counts : N_NODES ints = 200,000
//   total ~ 24.2 MB
// ---------------------------------------------------------------------------
#define WS_H_OFF      0
#define WS_ECSR_OFF   12800000
#define WS_COUNTS_OFF (WS_ECSR_OFF + 11200000)

// f32 -> bf16 round-to-nearest-even
__device__ __forceinline__ unsigned int f2bf(float f) {
    unsigned int u = __float_as_uint(f);
    unsigned int r = u + 0x7FFFu + ((u >> 16) & 1u);
    return r >> 16;
}
__device__ __forceinline__ float bf_lo(unsigned int u) {
    return __uint_as_float(u << 16);
}
__device__ __forceinline__ float bf_hi(unsigned int u) {
    return __uint_as_float(u & 0xFFFF0000u);
}

// ---------------------------------------------------------------------------
// ONE edge pass: k = atomicAdd(counts[row]); ecsr[row*PAD + k] = (col, f16(val))
// 2 edges/thread with vector loads.
// ---------------------------------------------------------------------------
__global__ void hist_scatter_kernel(const int* __restrict__ row,
                                    const int* __restrict__ col,
                                    const float* __restrict__ vals,
                                    int* __restrict__ counts,
                                    unsigned int* __restrict__ ecsr) {
    int i = blockIdx.x * blockDim.x + threadIdx.x;
    int e = i * 2;
    if (e >= N_EDGES) return;
    int2   rr = *reinterpret_cast<const int2*>(row + e);
    int2   cc = *reinterpret_cast<const int2*>(col + e);
    float2 vv = *reinterpret_cast<const float2*>(vals + e);

    int k0 = atomicAdd(&counts[rr.x], 1);
    int k1 = atomicAdd(&counts[rr.y], 1);

    unsigned int r0 = (unsigned int)cc.x |
        ((unsigned int)__half_as_ushort(__float2half_rn(vv.x)) << 16);
    unsigned int r1 = (unsigned int)cc.y |
        ((unsigned int)__half_as_ushort(__float2half_rn(vv.y)) << 16);

    if (k0 < PAD) ecsr[rr.x * PAD + k0] = r0;
    if (k1 < PAD) ecsr[rr.y * PAD + k1] = r1;
}

// ---------------------------------------------------------------------------
// GEMM: H16 = bf16(X @ W^T), row-major packed: uint j of row = cols (2j, 2j+1)
// (register-tiled 4x4 micro-tiles; LDS-swizzled W; same math as round 2-4)
// ---------------------------------------------------------------------------
__global__ __launch_bounds__(256) void gemm_xwT_kernel(const float* __restrict__ X,
                                                       const float* __restrict__ W,
                                                       unsigned int* __restrict__ H16) {
    __shared__ float Wt[D * D];    // 64 KiB
    __shared__ float xs[32 * D];   // 16 KiB
    const int t = threadIdx.x;
    const int base = blockIdx.x * 32;

    #pragma unroll
    for (int i = 0; i < 16; ++i) {
        int idx4 = t + i * 256;
        float4 w4 = reinterpret_cast<const float4*>(W)[idx4];
        int o  = idx4 >> 5;
        int d0 = (idx4 & 31) << 2;
        int oc = (o + d0) & 127;
        Wt[(d0 + 0) * D + oc] = w4.x;
        Wt[(d0 + 1) * D + oc] = w4.y;
        Wt[(d0 + 2) * D + oc] = w4.z;
        Wt[(d0 + 3) * D + oc] = w4.w;
    }

    #pragma unroll
    for (int i = 0; i < 4; ++i) {
        int idx4 = t + i * 256;
        int r  = idx4 >> 5;
        int d4 = idx4 & 31;
        int row = base + r;
        float4 x4 = {0.f, 0.f, 0.f, 0.f};
        if (row < N_NODES)
            x4 = reinterpret_cast<const float4*>(X + (size_t)row * D)[d4];
        reinterpret_cast<float4*>(xs)[idx4] = x4;
    }
    __syncthreads();

    const int rg = t >> 5;   // 0..7
    const int cg = t & 31;   // 0..31

    float acc[4][4];
    #pragma unroll
    for (int rr = 0; rr < 4; ++rr)
        #pragma unroll
        for (int cc = 0; cc < 4; ++cc) acc[rr][cc] = 0.f;

    #pragma unroll 4
    for (int d0 = 0; d0 < D; d0 += 4) {
        int jb = (cg * 4 + d0) & 127;
        float4 wc[4];
        #pragma unroll
        for (int k = 0; k < 4; ++k)
            wc[k] = *reinterpret_cast<const float4*>(&Wt[(d0 + k) * D + jb]);
        float4 xr[4];
        #pragma unroll
        for (int rr = 0; rr < 4; ++rr)
            xr[rr] = *reinterpret_cast<const float4*>(&xs[(rg * 4 + rr) * D + d0]);

        #pragma unroll
        for (int rr = 0; rr < 4; ++rr) {
            const float xv[4] = {xr[rr].x, xr[rr].y, xr[rr].z, xr[rr].w};
            #pragma unroll
            for (int k = 0; k < 4; ++k) {
                acc[rr][0] += xv[k] * wc[k].x;
                acc[rr][1] += xv[k] * wc[k].y;
                acc[rr][2] += xv[k] * wc[k].z;
                acc[rr][3] += xv[k] * wc[k].w;
            }
        }
    }

    #pragma unroll
    for (int rr = 0; rr < 4; ++rr) {
        int row = base + rg * 4 + rr;
        if (row < N_NODES) {
            uint2 packed;
            packed.x = f2bf(acc[rr][0]) | (f2bf(acc[rr][1]) << 16);
            packed.y = f2bf(acc[rr][2]) | (f2bf(acc[rr][3]) << 16);
            reinterpret_cast<uint2*>(H16 + (size_t)row * 64)[cg] = packed;
        }
    }
}

// ---------------------------------------------------------------------------
// Aggregate: one wave per row. 16 lanes per edge (uint4 = 8 cols/lane),
// 4 edges in parallel per iteration, unroll-2 for MLP.
//   out[row][:] = b[:] + sum_i val_i * bf16row(H[col_i])
// ---------------------------------------------------------------------------
__global__ __launch_bounds__(256) void aggregate_kernel(
        const int* __restrict__ counts, const unsigned int* __restrict__ ecsr,
        const unsigned int* __restrict__ H16,
        const float* __restrict__ b, float* __restrict__ out) {
    int gtid = blockIdx.x * blockDim.x + threadIdx.x;
    int row  = gtid >> 6;
    int lane = threadIdx.x & 63;
    if (row >= N_NODES) return;

    const int eg = lane >> 4;   // 0..3: edge sub-group
    const int c  = lane & 15;   // 0..15: column group (cols 8c..8c+7)

    int deg = counts[row];
    if (deg > PAD) deg = PAD;
    const unsigned int* seg = ecsr + row * PAD;

    float a[8];
    #pragma unroll
    for (int k = 0; k < 8; ++k) a[k] = 0.f;

    #define EDGE_BODY(IDX)                                                        \
        {                                                                         \
            unsigned int rec = seg[(IDX)];                                        \
            int   cx = rec & 0xFFFFu;                                             \
            float v  = __half2float(__ushort_as_half((unsigned short)(rec >> 16)));\
            uint4 h = *reinterpret_cast<const uint4*>(H16 + (size_t)cx * 64 + c * 4);\
            a[0] += v * bf_lo(h.x); a[1] += v * bf_hi(h.x);                       \
            a[2] += v * bf_lo(h.y); a[3] += v * bf_hi(h.y);                       \
            a[4] += v * bf_lo(h.z); a[5] += v * bf_hi(h.z);                       \
            a[6] += v * bf_lo(h.w); a[7] += v * bf_hi(h.w);                       \
        }

    int i = eg;
    for (; i + 4 < deg; i += 8) {
        EDGE_BODY(i);
        EDGE_BODY(i + 4);
    }
    if (i < deg) EDGE_BODY(i);
    #undef EDGE_BODY

    // reduce across the 4 edge sub-groups (lanes ^16, ^32)
    #pragma unroll
    for (int k = 0; k < 8; ++k) {
        a[k] += __shfl_xor(a[k], 16, 64);
        a[k] += __shfl_xor(a[k], 32, 64);
    }

    if (eg == 0) {
        float4 b0 = *reinterpret_cast<const float4*>(b + c * 8);
        float4 b1 = *reinterpret_cast<const float4*>(b + c * 8 + 4);
        float4 o0 = {a[0] + b0.x, a[1] + b0.y, a[2] + b0.z, a[3] + b0.w};
        float4 o1 = {a[4] + b1.x, a[5] + b1.y, a[6] + b1.z, a[7] + b1.w};
        float* dst = out + (size_t)row * D + c * 8;
        *reinterpret_cast<float4*>(dst)     = o0;
        *reinterpret_cast<float4*>(dst + 4) = o1;
    }
}

// ---------------------------------------------------------------------------
extern "C" void kernel_launch(void* const* d_in, const int* in_sizes, int n_in,
                              void* d_out, int out_size, void* d_ws, size_t ws_size,
                              hipStream_t stream) {
    const int*   adj_row  = (const int*)d_in[0];
    const int*   adj_col  = (const int*)d_in[1];
    const float* adj_vals = (const float*)d_in[2];
    const float* features = (const float*)d_in[3];
    const float* W        = (const float*)d_in[4];
    const float* b        = (const float*)d_in[5];
    float*       out      = (float*)d_out;

    char* ws = (char*)d_ws;
    unsigned int* H16    = (unsigned int*)(ws + WS_H_OFF);
    unsigned int* ecsr   = (unsigned int*)(ws + WS_ECSR_OFF);
    int*          counts = (int*)(ws + WS_COUNTS_OFF);

    // 1. counts = 0 (async memset is graph-capture safe)
    hipMemsetAsync(counts, 0, N_NODES * sizeof(int), stream);
    // 2. single edge pass: histogram + padded-CSR scatter
    {
        int threads = N_EDGES / 2;
        hist_scatter_kernel<<<(threads + 255) / 256, 256, 0, stream>>>(
            adj_row, adj_col, adj_vals, counts, ecsr);
    }
    // 3. H16 = bf16(X @ W^T)
    gemm_xwT_kernel<<<(N_NODES + 31) / 32, 256, 0, stream>>>(features, W, H16);
    // 4. aggregate: out = b + segment_sum(val * H[col])
    {
        int blocks = (N_NODES * 64 + 255) / 256;   // one wave per row
        aggregate_kernel<<<blocks, 256, 0, stream>>>(counts, ecsr, H16, b, out);
    }
}

// Round 7
// 129.382 us; speedup vs baseline: 1.6913x; 1.0215x over previous
//
#include <hip/hip_runtime.h>
#include <hip/hip_fp16.h>

#define N_NODES 50000
#define N_EDGES 800000
#define D 128
#define PAD 56   // padded-CSR slots per row; P(Poisson(16) > 56) ~ 1e-14/node

#define GEMM_BLOCKS 1563   // ceil(50000/32)
#define HIST_BLOCKS 782    // ceil(200000 threads / 256), 4 edges/thread
#define FUSED_BLOCKS 2346  // 3 * 782 : bid%3==2 -> hist, else gemm

// ---------------------------------------------------------------------------
// Workspace layout (bytes, 16B-aligned):
//   H16    : N_NODES*64 uints (bf16x2 packed) = 12,800,000
//   ecsr   : N_NODES*PAD uints (col u16 | f16 val << 16) = 11,200,000
//   counts : N_NODES ints = 200,000
// ---------------------------------------------------------------------------
#define WS_H_OFF      0
#define WS_ECSR_OFF   12800000
#define WS_COUNTS_OFF (WS_ECSR_OFF + 11200000)

// f32 -> bf16 round-to-nearest-even
__device__ __forceinline__ unsigned int f2bf(float f) {
    unsigned int u = __float_as_uint(f);
    unsigned int r = u + 0x7FFFu + ((u >> 16) & 1u);
    return r >> 16;
}
__device__ __forceinline__ float bf_lo(unsigned int u) {
    return __uint_as_float(u << 16);
}
__device__ __forceinline__ float bf_hi(unsigned int u) {
    return __uint_as_float(u & 0xFFFF0000u);
}

// ---------------------------------------------------------------------------
// Fused kernel: gemm role (H16 = bf16(X @ W^T)) + hist role (CSR build).
// Roles interleave 2:1 across the grid so every CU runs a latency-bound
// hist block alongside VALU-bound gemm blocks.
// LDS: only Wt2 (32 KiB, bf16-pair packed) -> 5 blocks/CU.
// ---------------------------------------------------------------------------
__global__ __launch_bounds__(256) void fused_gemm_hist_kernel(
        const float* __restrict__ X, const float* __restrict__ W,
        unsigned int* __restrict__ H16,
        const int* __restrict__ row, const int* __restrict__ col,
        const float* __restrict__ vals,
        int* __restrict__ counts, unsigned int* __restrict__ ecsr) {
    const int bid = blockIdx.x;
    const int t   = threadIdx.x;

    if ((bid % 3) == 2) {
        // ---------------- hist role: 4 edges/thread ----------------
        int ht = (bid / 3) * 256 + t;
        if (ht >= N_EDGES / 4) return;
        int e = ht * 4;
        int4   rr = *reinterpret_cast<const int4*>(row + e);
        int4   cc = *reinterpret_cast<const int4*>(col + e);
        float4 vv = *reinterpret_cast<const float4*>(vals + e);

        int k0 = atomicAdd(&counts[rr.x], 1);
        int k1 = atomicAdd(&counts[rr.y], 1);
        int k2 = atomicAdd(&counts[rr.z], 1);
        int k3 = atomicAdd(&counts[rr.w], 1);

        unsigned int r0 = (unsigned int)cc.x |
            ((unsigned int)__half_as_ushort(__float2half_rn(vv.x)) << 16);
        unsigned int r1 = (unsigned int)cc.y |
            ((unsigned int)__half_as_ushort(__float2half_rn(vv.y)) << 16);
        unsigned int r2 = (unsigned int)cc.z |
            ((unsigned int)__half_as_ushort(__float2half_rn(vv.z)) << 16);
        unsigned int r3 = (unsigned int)cc.w |
            ((unsigned int)__half_as_ushort(__float2half_rn(vv.w)) << 16);

        if (k0 < PAD) ecsr[rr.x * PAD + k0] = r0;
        if (k1 < PAD) ecsr[rr.y * PAD + k1] = r1;
        if (k2 < PAD) ecsr[rr.z * PAD + k2] = r2;
        if (k3 < PAD) ecsr[rr.w * PAD + k3] = r3;
        return;
    }

    // ---------------- gemm role ----------------
    __shared__ unsigned int Wt2[64 * D];   // 32 KiB: [dpair][ocol] bf16x2
    int g = (bid / 3) * 2 + (bid % 3);
    if (g >= GEMM_BLOCKS) return;
    const int base = g * 32;

    // Stage W as bf16 pairs: Wt2[(d/2)*128 + o] = bf(W[o][d]) | bf(W[o][d+1])<<16
    #pragma unroll
    for (int i = 0; i < 16; ++i) {
        int idx4 = t + i * 256;
        float4 w4 = reinterpret_cast<const float4*>(W)[idx4];
        int o  = idx4 >> 5;
        int d0 = (idx4 & 31) << 2;
        int dp = d0 >> 1;
        Wt2[dp * D + o]       = f2bf(w4.x) | (f2bf(w4.y) << 16);
        Wt2[(dp + 1) * D + o] = f2bf(w4.z) | (f2bf(w4.w) << 16);
    }
    __syncthreads();

    const int rg = t >> 5;   // 0..7
    const int cg = t & 31;   // 0..31

    // clamp rows for safe loads; stores guarded
    int rws[4];
    #pragma unroll
    for (int rr = 0; rr < 4; ++rr) {
        int r = base + rg * 4 + rr;
        rws[rr] = (r < N_NODES) ? r : (N_NODES - 1);
    }

    float acc[4][4];
    #pragma unroll
    for (int rr = 0; rr < 4; ++rr)
        #pragma unroll
        for (int cc = 0; cc < 4; ++cc) acc[rr][cc] = 0.f;

    const float4* X4 = reinterpret_cast<const float4*>(X);

    #pragma unroll 4
    for (int d0 = 0; d0 < D; d0 += 4) {
        int dp = d0 >> 1;
        uint4 wa = *reinterpret_cast<const uint4*>(&Wt2[dp * D + cg * 4]);
        uint4 wb = *reinterpret_cast<const uint4*>(&Wt2[(dp + 1) * D + cg * 4]);
        // unpack once per step (shared across the 4 rows)
        float wl0[4] = {bf_lo(wa.x), bf_lo(wa.y), bf_lo(wa.z), bf_lo(wa.w)};  // d0
        float wh0[4] = {bf_hi(wa.x), bf_hi(wa.y), bf_hi(wa.z), bf_hi(wa.w)};  // d0+1
        float wl1[4] = {bf_lo(wb.x), bf_lo(wb.y), bf_lo(wb.z), bf_lo(wb.w)};  // d0+2
        float wh1[4] = {bf_hi(wb.x), bf_hi(wb.y), bf_hi(wb.z), bf_hi(wb.w)};  // d0+3

        #pragma unroll
        for (int rr = 0; rr < 4; ++rr) {
            // wave-broadcast load (32 lanes same address), L1-resident
            float4 xr = X4[(size_t)rws[rr] * 32 + (d0 >> 2)];
            #pragma unroll
            for (int c = 0; c < 4; ++c)
                acc[rr][c] += xr.x * wl0[c] + xr.y * wh0[c]
                            + xr.z * wl1[c] + xr.w * wh1[c];
        }
    }

    #pragma unroll
    for (int rr = 0; rr < 4; ++rr) {
        int r = base + rg * 4 + rr;
        if (r < N_NODES) {
            uint2 packed;
            packed.x = f2bf(acc[rr][0]) | (f2bf(acc[rr][1]) << 16);
            packed.y = f2bf(acc[rr][2]) | (f2bf(acc[rr][3]) << 16);
            reinterpret_cast<uint2*>(H16 + (size_t)r * 64)[cg] = packed;
        }
    }
}

// ---------------------------------------------------------------------------
// Aggregate: one wave per row. 16 lanes per edge (uint4 = 8 cols/lane),
// 4 edges in parallel per iteration, unroll-2 for MLP.
// ---------------------------------------------------------------------------
__global__ __launch_bounds__(256) void aggregate_kernel(
        const int* __restrict__ counts, const unsigned int* __restrict__ ecsr,
        const unsigned int* __restrict__ H16,
        const float* __restrict__ b, float* __restrict__ out) {
    int gtid = blockIdx.x * blockDim.x + threadIdx.x;
    int row  = gtid >> 6;
    int lane = threadIdx.x & 63;
    if (row >= N_NODES) return;

    const int eg = lane >> 4;   // 0..3: edge sub-group
    const int c  = lane & 15;   // 0..15: column group (cols 8c..8c+7)

    int deg = counts[row];
    if (deg > PAD) deg = PAD;
    const unsigned int* seg = ecsr + row * PAD;

    float a[8];
    #pragma unroll
    for (int k = 0; k < 8; ++k) a[k] = 0.f;

    #define EDGE_BODY(IDX)                                                        \
        {                                                                         \
            unsigned int rec = seg[(IDX)];                                        \
            int   cx = rec & 0xFFFFu;                                             \
            float v  = __half2float(__ushort_as_half((unsigned short)(rec >> 16)));\
            uint4 h = *reinterpret_cast<const uint4*>(H16 + (size_t)cx * 64 + c * 4);\
            a[0] += v * bf_lo(h.x); a[1] += v * bf_hi(h.x);                       \
            a[2] += v * bf_lo(h.y); a[3] += v * bf_hi(h.y);                       \
            a[4] += v * bf_lo(h.z); a[5] += v * bf_hi(h.z);                       \
            a[6] += v * bf_lo(h.w); a[7] += v * bf_hi(h.w);                       \
        }

    int i = eg;
    for (; i + 4 < deg; i += 8) {
        EDGE_BODY(i);
        EDGE_BODY(i + 4);
    }
    if (i < deg) EDGE_BODY(i);
    #undef EDGE_BODY

    #pragma unroll
    for (int k = 0; k < 8; ++k) {
        a[k] += __shfl_xor(a[k], 16, 64);
        a[k] += __shfl_xor(a[k], 32, 64);
    }

    if (eg == 0) {
        float4 b0 = *reinterpret_cast<const float4*>(b + c * 8);
        float4 b1 = *reinterpret_cast<const float4*>(b + c * 8 + 4);
        float4 o0 = {a[0] + b0.x, a[1] + b0.y, a[2] + b0.z, a[3] + b0.w};
        float4 o1 = {a[4] + b1.x, a[5] + b1.y, a[6] + b1.z, a[7] + b1.w};
        float* dst = out + (size_t)row * D + c * 8;
        *reinterpret_cast<float4*>(dst)     = o0;
        *reinterpret_cast<float4*>(dst + 4) = o1;
    }
}

// ---------------------------------------------------------------------------
extern "C" void kernel_launch(void* const* d_in, const int* in_sizes, int n_in,
                              void* d_out, int out_size, void* d_ws, size_t ws_size,
                              hipStream_t stream) {
    const int*   adj_row  = (const int*)d_in[0];
    const int*   adj_col  = (const int*)d_in[1];
    const float* adj_vals = (const float*)d_in[2];
    const float* features = (const float*)d_in[3];
    const float* W        = (const float*)d_in[4];
    const float* b        = (const float*)d_in[5];
    float*       out      = (float*)d_out;

    char* ws = (char*)d_ws;
    unsigned int* H16    = (unsigned int*)(ws + WS_H_OFF);
    unsigned int* ecsr   = (unsigned int*)(ws + WS_ECSR_OFF);
    int*          counts = (int*)(ws + WS_COUNTS_OFF);

    // 1. counts = 0
    hipMemsetAsync(counts, 0, N_NODES * sizeof(int), stream);
    // 2. fused: gemm (H16 = bf16(X @ W^T)) + hist/padded-CSR build
    fused_gemm_hist_kernel<<<FUSED_BLOCKS, 256, 0, stream>>>(
        features, W, H16, adj_row, adj_col, adj_vals, counts, ecsr);
    // 3. aggregate: out = b + segment_sum(val * H[col])
    {
        int blocks = (N_NODES * 64 + 255) / 256;   // one wave per row
        aggregate_kernel<<<blocks, 256, 0, stream>>>(counts, ecsr, H16, b, out);
    }
}